// Round 2
// baseline (24643.979 us; speedup 1.0000x reference)
//
#include <hip/hip_runtime.h>
#include <math.h>

// Problem constants
#define N_ROWS 16384
#define VOCAB  8192
#define EMB    256

// Tiling
#define BN 128                    // z rows per block
#define BV 128                    // codebook rows per v-tile
#define BK 32                     // K chunk staged in LDS
#define VSPLIT 8                  // blocks splitting the V dimension (grid = 128x8 = 1024 = 4/CU)
#define VRANGE (VOCAB / VSPLIT)   // 1024
#define NVT    (VRANGE / BV)      // 8 v-tiles per block
#define LSTR   36                 // LDS row stride in floats: 144B = 16B-aligned, diagonal banks

// ---------------------------------------------------------------------------
// Kernel 1: e_sq[v] = ||codebook[v]||^2. One wave per row.
// ---------------------------------------------------------------------------
__global__ void esq_kernel(const float* __restrict__ cb, float* __restrict__ esq) {
    const int wave = threadIdx.x >> 6;
    const int lane = threadIdx.x & 63;
    const int row  = blockIdx.x * 4 + wave;
    const float4 v = *(const float4*)(cb + (size_t)row * EMB + lane * 4);
    float s = v.x * v.x + v.y * v.y + v.z * v.z + v.w * v.w;
    #pragma unroll
    for (int off = 32; off > 0; off >>= 1) s += __shfl_down(s, off, 64);
    if (lane == 0) esq[row] = s;
}

// ---------------------------------------------------------------------------
// Kernel 2: tiled fp32 distance + running argmin.
// dist'(n,v) = e_sq[v] - 2*dot(z_n, e_v)   (z_sq dropped: constant per row)
// Row-major LDS tiles [row][LSTR]; staging is b128 writes (conflict-free
// diagonal); fragment reads are b128 along k with consecutive-row lane
// assignment so the 8 distinct addresses tile all 32 banks.
// ---------------------------------------------------------------------------
__global__ __launch_bounds__(256, 4)
void dist_argmin_kernel(const float* __restrict__ z,
                        const float* __restrict__ cb,
                        const float* __restrict__ esq,
                        float* __restrict__ pdist,
                        int*   __restrict__ pidx) {
    __shared__ float zs[BN][LSTR];     // 18 KB
    __shared__ float es[BV][LSTR];     // 18 KB
    __shared__ float rdist[16][16];    // 1 KB
    __shared__ int   ridx [16][16];    // 1 KB   -> total ~38.9 KB => 4 blocks/CU

    const int bn    = blockIdx.x;
    const int vs    = blockIdx.y;
    const int row0  = bn * BN;
    const int vbase = vs * VRANGE;

    const int tid  = threadIdx.x;
    const int wave = tid >> 6;
    const int lane = tid & 63;
    const int wly  = (lane >> 3) & 7;       // row-group lane 0..7
    const int wlx  = lane & 7;              // col-group lane 0..7

    // waves 0,1 -> rows 0..63 | waves 2,3 -> rows 64..127
    // waves 0,2 -> cols 0..63 | waves 1,3 -> cols 64..127
    const int wbase = (wave >> 1) * 64;
    const int cbase = (wave & 1) * 64;
    const int arow  = wbase + wly;          // thread's rows: arow + 8*i
    const int bcol  = cbase + wlx;          // thread's cols: bcol + 8*j
    const int rowSlot = (wave >> 1) * 8 + wly;   // 0..15
    const int colSlot = (wave & 1) * 8 + wlx;    // 0..15

    // staging indices: c4 = tid&7 (lane-fastest -> 128B coalesced global loads)
    const int sc4 = tid & 7;
    const int sr0 = tid >> 3;               // + 32*t, t=0..3

    float best[8];
    int   bidx[8];
    #pragma unroll
    for (int i = 0; i < 8; ++i) { best[i] = INFINITY; bidx[i] = 0; }

    for (int vt = 0; vt < NVT; ++vt) {
        const int v0 = vbase + vt * BV;

        float acc[8][8];
        #pragma unroll
        for (int i = 0; i < 8; ++i)
            #pragma unroll
            for (int j = 0; j < 8; ++j) acc[i][j] = 0.0f;

        for (int kt = 0; kt < EMB / BK; ++kt) {
            // Stage both tiles: 4 float4 per thread per tile, b128 LDS writes.
            #pragma unroll
            for (int t = 0; t < 4; ++t) {
                const int r = sr0 + 32 * t;
                const float4 va = *(const float4*)(z  + (size_t)(row0 + r) * EMB + kt * BK + sc4 * 4);
                *(float4*)&zs[r][sc4 * 4] = va;
                const float4 vb = *(const float4*)(cb + (size_t)(v0 + r) * EMB + kt * BK + sc4 * 4);
                *(float4*)&es[r][sc4 * 4] = vb;
            }
            __syncthreads();

            // Inner product: 8 k-chunks of 4; 16 b128 reads per 256 FMAs.
            #pragma unroll
            for (int k0 = 0; k0 < BK / 4; ++k0) {
                const int kk = k0 * 4;
                float4 a4[8];
                #pragma unroll
                for (int i = 0; i < 8; ++i)
                    a4[i] = *(const float4*)&zs[arow + 8 * i][kk];
                #pragma unroll
                for (int j = 0; j < 8; ++j) {
                    const float4 b4 = *(const float4*)&es[bcol + 8 * j][kk];
                    #pragma unroll
                    for (int i = 0; i < 8; ++i) {
                        acc[i][j] += a4[i].x * b4.x;
                        acc[i][j] += a4[i].y * b4.y;
                        acc[i][j] += a4[i].z * b4.z;
                        acc[i][j] += a4[i].w * b4.w;
                    }
                }
            }
            __syncthreads();
        }

        // Epilogue: dist' = e_sq[v] - 2*acc; running argmin.
        // j ascending => v ascending within thread; vt ascending globally.
        #pragma unroll
        for (int j = 0; j < 8; ++j) {
            const int v = v0 + bcol + 8 * j;
            const float ev = esq[v];
            #pragma unroll
            for (int i = 0; i < 8; ++i) {
                const float d = ev - 2.0f * acc[i][j];
                if (d < best[i]) { best[i] = d; bidx[i] = v; }
            }
        }
    }

    // Cross-thread argmin: 16 col-groups share each row.
    for (int i = 0; i < 8; ++i) {
        rdist[rowSlot][colSlot] = best[i];
        ridx [rowSlot][colSlot] = bidx[i];
        __syncthreads();
        if (colSlot == 0) {
            float bd = rdist[rowSlot][0];
            int   bi = ridx [rowSlot][0];
            #pragma unroll
            for (int t = 1; t < 16; ++t) {
                const float d  = rdist[rowSlot][t];
                const int   ii = ridx [rowSlot][t];
                if (d < bd || (d == bd && ii < bi)) { bd = d; bi = ii; }
            }
            const int row = row0 + wbase + 8 * i + wly;   // matches arow + 8*i
            pdist[(size_t)vs * N_ROWS + row] = bd;
            pidx [(size_t)vs * N_ROWS + row] = bi;
        }
        __syncthreads();
    }
}

// ---------------------------------------------------------------------------
// Kernel 3: merge VSPLIT partials; emit token (float), gather z_q, histogram.
// One wave per row.
// ---------------------------------------------------------------------------
__global__ void combine_kernel(const float* __restrict__ pdist,
                               const int*   __restrict__ pidx,
                               const float* __restrict__ cb,
                               float* __restrict__ tokens,
                               float* __restrict__ zq,
                               float* __restrict__ cnt) {
    const int wave = threadIdx.x >> 6;
    const int lane = threadIdx.x & 63;
    const int row  = blockIdx.x * 4 + wave;

    float bd = INFINITY;
    int   bi = 0;
    #pragma unroll
    for (int s = 0; s < VSPLIT; ++s) {
        const float d  = pdist[(size_t)s * N_ROWS + row];
        const int   ii = pidx [(size_t)s * N_ROWS + row];
        if (d < bd || (d == bd && ii < bi)) { bd = d; bi = ii; }
    }
    if (lane == 0) {
        tokens[row] = (float)bi;
        atomicAdd(&cnt[bi], 1.0f);
    }
    const float4 v = *(const float4*)(cb + (size_t)bi * EMB + lane * 4);
    *(float4*)(zq + (size_t)row * EMB + lane * 4) = v;
}

// ---------------------------------------------------------------------------
// d_out layout (float32, reference return order):
//   [0, N) tokens | [N, N+N*EMB) z_q | [..., +VOCAB) ref_count
// Workspace: esq (VOCAB) | pdist (VSPLIT*N) | pidx (VSPLIT*N)  ~= 1.06 MB
// ---------------------------------------------------------------------------
extern "C" void kernel_launch(void* const* d_in, const int* in_sizes, int n_in,
                              void* d_out, int out_size, void* d_ws, size_t ws_size,
                              hipStream_t stream) {
    const float* z  = (const float*)d_in[0];
    const float* cb = (const float*)d_in[1];

    float* out    = (float*)d_out;
    float* tokens = out;
    float* zq     = out + N_ROWS;
    float* cnt    = out + N_ROWS + (size_t)N_ROWS * EMB;

    float* esq   = (float*)d_ws;
    float* pdist = esq + VOCAB;
    int*   pidx  = (int*)(pdist + (size_t)VSPLIT * N_ROWS);

    hipMemsetAsync(cnt, 0, VOCAB * sizeof(float), stream);

    esq_kernel<<<VOCAB / 4, 256, 0, stream>>>(cb, esq);
    dist_argmin_kernel<<<dim3(N_ROWS / BN, VSPLIT), 256, 0, stream>>>(z, cb, esq, pdist, pidx);
    combine_kernel<<<N_ROWS / 4, 256, 0, stream>>>(pdist, pidx, cb, tokens, zq, cnt);
}

// Round 3
// 999.533 us; speedup vs baseline: 24.6555x; 24.6555x over previous
//
#include <hip/hip_runtime.h>
#include <math.h>

// Problem constants
#define N_ROWS 16384
#define VOCAB  8192
#define EMB    256

// Tiling
#define BN 128                    // z rows per block
#define BV 128                    // codebook rows per v-tile
#define BK 32                     // K chunk staged in LDS
#define VSPLIT 8                  // V split across blocks (grid 128x8 = 1024 = 4/CU)
#define VRANGE (VOCAB / VSPLIT)   // 1024
#define NVT    (VRANGE / BV)      // 8 v-tiles per block
#define LSTR   36                 // LDS row stride (floats): 144B, 16B-aligned, diagonal banks

// ---------------------------------------------------------------------------
// Kernel 1: e_sq[v] = ||codebook[v]||^2. One wave per row.
// ---------------------------------------------------------------------------
__global__ void esq_kernel(const float* __restrict__ cb, float* __restrict__ esq) {
    const int wave = threadIdx.x >> 6;
    const int lane = threadIdx.x & 63;
    const int row  = blockIdx.x * 4 + wave;
    const float4 v = *(const float4*)(cb + (size_t)row * EMB + lane * 4);
    float s = v.x * v.x + v.y * v.y + v.z * v.z + v.w * v.w;
    #pragma unroll
    for (int off = 32; off > 0; off >>= 1) s += __shfl_down(s, off, 64);
    if (lane == 0) esq[row] = s;
}

// ---------------------------------------------------------------------------
// Kernel 2: tiled fp32 distance + running argmin.
// dist'(n,v) = e_sq[v] - 2*dot(z_n, e_v)   (z_sq dropped: constant per row)
// LDS layout: row-major [row][36] -> b128 staging writes conflict-free
// (diagonal), b128 fragment reads tile all 32 banks (verified: conflicts
// 5.1e7 -> 1.1e6 in round 2).
// __launch_bounds__(256,2): round 2 proved (256,4) forces VGPR=64 and spills
// the 8x8 accumulator to scratch (46.8 GB writes). HW reaches 4 waves/SIMD
// as long as the natural allocation stays <=128 VGPRs.
// ---------------------------------------------------------------------------
__global__ __launch_bounds__(256, 2)
void dist_argmin_kernel(const float* __restrict__ z,
                        const float* __restrict__ cb,
                        const float* __restrict__ esq,
                        float* __restrict__ pdist,
                        int*   __restrict__ pidx) {
    __shared__ float zs[BN][LSTR];     // 18 KB
    __shared__ float es[BV][LSTR];     // 18 KB
    __shared__ float rdist[16][16];    // 1 KB
    __shared__ int   ridx [16][16];    // 1 KB   -> ~38.9 KB => 4 blocks/CU by LDS

    const int bn    = blockIdx.x;
    const int vs    = blockIdx.y;
    const int row0  = bn * BN;
    const int vbase = vs * VRANGE;

    const int tid  = threadIdx.x;
    const int wave = tid >> 6;
    const int lane = tid & 63;
    const int wly  = (lane >> 3) & 7;
    const int wlx  = lane & 7;

    const int wbase = (wave >> 1) * 64;
    const int cbase = (wave & 1) * 64;
    const int arow  = wbase + wly;          // thread's rows: arow + 8*i
    const int bcol  = cbase + wlx;          // thread's cols: bcol + 8*j
    const int rowSlot = (wave >> 1) * 8 + wly;
    const int colSlot = (wave & 1) * 8 + wlx;

    const int sc4 = tid & 7;
    const int sr0 = tid >> 3;

    float best[8];
    int   bidx[8];
    #pragma unroll
    for (int i = 0; i < 8; ++i) { best[i] = INFINITY; bidx[i] = 0; }

    for (int vt = 0; vt < NVT; ++vt) {
        const int v0 = vbase + vt * BV;

        float acc[8][8];
        #pragma unroll
        for (int i = 0; i < 8; ++i)
            #pragma unroll
            for (int j = 0; j < 8; ++j) acc[i][j] = 0.0f;

        #pragma unroll 1
        for (int kt = 0; kt < EMB / BK; ++kt) {
            // Stage both tiles: 4 float4 per thread per tile, b128 LDS writes.
            #pragma unroll
            for (int t = 0; t < 4; ++t) {
                const int r = sr0 + 32 * t;
                const float4 va = *(const float4*)(z  + (size_t)(row0 + r) * EMB + kt * BK + sc4 * 4);
                *(float4*)&zs[r][sc4 * 4] = va;
                const float4 vb = *(const float4*)(cb + (size_t)(v0 + r) * EMB + kt * BK + sc4 * 4);
                *(float4*)&es[r][sc4 * 4] = vb;
            }
            __syncthreads();

            // 8 k-chunks of 4; 16 b128 LDS reads per 256 FMAs.
            // unroll 1: full unroll keeps multiple 36-reg fragment sets live
            // and risks the >128-VGPR occupancy cliff.
            #pragma unroll 1
            for (int k0 = 0; k0 < BK / 4; ++k0) {
                const int kk = k0 * 4;
                float a[8][4];
                #pragma unroll
                for (int i = 0; i < 8; ++i) {
                    const float4 a4 = *(const float4*)&zs[arow + 8 * i][kk];
                    a[i][0] = a4.x; a[i][1] = a4.y; a[i][2] = a4.z; a[i][3] = a4.w;
                }
                #pragma unroll
                for (int j = 0; j < 8; ++j) {
                    const float4 b4 = *(const float4*)&es[bcol + 8 * j][kk];
                    #pragma unroll
                    for (int i = 0; i < 8; ++i) {
                        acc[i][j] += a[i][0] * b4.x;
                        acc[i][j] += a[i][1] * b4.y;
                        acc[i][j] += a[i][2] * b4.z;
                        acc[i][j] += a[i][3] * b4.w;
                    }
                }
            }
            __syncthreads();
        }

        // Epilogue: dist' = e_sq[v] - 2*acc; running argmin.
        #pragma unroll
        for (int j = 0; j < 8; ++j) {
            const int v = v0 + bcol + 8 * j;
            const float ev = esq[v];
            #pragma unroll
            for (int i = 0; i < 8; ++i) {
                const float d = ev - 2.0f * acc[i][j];
                if (d < best[i]) { best[i] = d; bidx[i] = v; }
            }
        }
    }

    // Cross-thread argmin: 16 col-groups share each row.
    for (int i = 0; i < 8; ++i) {
        rdist[rowSlot][colSlot] = best[i];
        ridx [rowSlot][colSlot] = bidx[i];
        __syncthreads();
        if (colSlot == 0) {
            float bd = rdist[rowSlot][0];
            int   bi = ridx [rowSlot][0];
            #pragma unroll
            for (int t = 1; t < 16; ++t) {
                const float d  = rdist[rowSlot][t];
                const int   ii = ridx [rowSlot][t];
                if (d < bd || (d == bd && ii < bi)) { bd = d; bi = ii; }
            }
            const int row = row0 + wbase + 8 * i + wly;
            pdist[(size_t)vs * N_ROWS + row] = bd;
            pidx [(size_t)vs * N_ROWS + row] = bi;
        }
        __syncthreads();
    }
}

// ---------------------------------------------------------------------------
// Kernel 3: merge VSPLIT partials; emit token (float), gather z_q, histogram.
// ---------------------------------------------------------------------------
__global__ void combine_kernel(const float* __restrict__ pdist,
                               const int*   __restrict__ pidx,
                               const float* __restrict__ cb,
                               float* __restrict__ tokens,
                               float* __restrict__ zq,
                               float* __restrict__ cnt) {
    const int wave = threadIdx.x >> 6;
    const int lane = threadIdx.x & 63;
    const int row  = blockIdx.x * 4 + wave;

    float bd = INFINITY;
    int   bi = 0;
    #pragma unroll
    for (int s = 0; s < VSPLIT; ++s) {
        const float d  = pdist[(size_t)s * N_ROWS + row];
        const int   ii = pidx [(size_t)s * N_ROWS + row];
        if (d < bd || (d == bd && ii < bi)) { bd = d; bi = ii; }
    }
    if (lane == 0) {
        tokens[row] = (float)bi;
        atomicAdd(&cnt[bi], 1.0f);
    }
    const float4 v = *(const float4*)(cb + (size_t)bi * EMB + lane * 4);
    *(float4*)(zq + (size_t)row * EMB + lane * 4) = v;
}

// ---------------------------------------------------------------------------
// d_out layout (float32, reference return order):
//   [0, N) tokens | [N, N+N*EMB) z_q | [..., +VOCAB) ref_count
// Workspace: esq (VOCAB) | pdist (VSPLIT*N) | pidx (VSPLIT*N)  ~= 1.06 MB
// ---------------------------------------------------------------------------
extern "C" void kernel_launch(void* const* d_in, const int* in_sizes, int n_in,
                              void* d_out, int out_size, void* d_ws, size_t ws_size,
                              hipStream_t stream) {
    const float* z  = (const float*)d_in[0];
    const float* cb = (const float*)d_in[1];

    float* out    = (float*)d_out;
    float* tokens = out;
    float* zq     = out + N_ROWS;
    float* cnt    = out + N_ROWS + (size_t)N_ROWS * EMB;

    float* esq   = (float*)d_ws;
    float* pdist = esq + VOCAB;
    int*   pidx  = (int*)(pdist + (size_t)VSPLIT * N_ROWS);

    hipMemsetAsync(cnt, 0, VOCAB * sizeof(float), stream);

    esq_kernel<<<VOCAB / 4, 256, 0, stream>>>(cb, esq);
    dist_argmin_kernel<<<dim3(N_ROWS / BN, VSPLIT), 256, 0, stream>>>(z, cb, esq, pdist, pidx);
    combine_kernel<<<N_ROWS / 4, 256, 0, stream>>>(pdist, pidx, cb, tokens, zq, cnt);
}

// Round 4
// 615.239 us; speedup vs baseline: 40.0559x; 1.6246x over previous
//
#include <hip/hip_runtime.h>
#include <math.h>

#define N_ROWS 16384
#define VOCAB  8192
#define EMB    256

// ---- MFMA path tiling ----
#define BM 128
#define BV 128
#define BK 32                      // halfs per K-step (one 16x16x32 MFMA k)
#define VSPLIT 8                   // grid (128, 8); per block: 8 v-tiles of 128
#define VRANGE (VOCAB / VSPLIT)    // 1024
#define NVT    (VRANGE / BV)       // 8
#define LSH    40                  // LDS tile row stride in halfs (80 B, 16B-aligned)
#define TAU    0.01f               // rescue margin (approx dist error <= ~1e-3)

typedef _Float16 half8 __attribute__((ext_vector_type(8)));
typedef _Float16 half4 __attribute__((ext_vector_type(4)));
typedef float floatx4 __attribute__((ext_vector_type(4)));

// ---------------------------------------------------------------------------
// esq[v] = ||cb[v]||^2 (fp32, exact). One wave per row.
// ---------------------------------------------------------------------------
__global__ void esq_kernel(const float* __restrict__ cb, float* __restrict__ esq) {
    const int wave = threadIdx.x >> 6;
    const int lane = threadIdx.x & 63;
    const int row  = blockIdx.x * 4 + wave;
    const float4 v = *(const float4*)(cb + (size_t)row * EMB + lane * 4);
    float s = v.x * v.x + v.y * v.y + v.z * v.z + v.w * v.w;
    #pragma unroll
    for (int off = 32; off > 0; off >>= 1) s += __shfl_down(s, off, 64);
    if (lane == 0) esq[row] = s;
}

// ---------------------------------------------------------------------------
// Split fp32 -> fp16 hi + fp16 lo for z and cb. One float4 per thread.
// ---------------------------------------------------------------------------
__global__ void split_kernel(const float* __restrict__ z, const float* __restrict__ cb,
                             _Float16* __restrict__ zh, _Float16* __restrict__ zl,
                             _Float16* __restrict__ ch, _Float16* __restrict__ cl) {
    const size_t gid = (size_t)blockIdx.x * blockDim.x + threadIdx.x;
    const size_t ZQ4 = (size_t)N_ROWS * EMB / 4;     // z float4 count
    const float* src; _Float16 *dh, *dl; size_t idx4;
    if (gid < ZQ4) { src = z;  dh = zh; dl = zl; idx4 = gid; }
    else           { src = cb; dh = ch; dl = cl; idx4 = gid - ZQ4; }
    const float4 f = *(const float4*)(src + idx4 * 4);
    half4 h, l;
    h.x = (_Float16)f.x; l.x = (_Float16)(f.x - (float)h.x);
    h.y = (_Float16)f.y; l.y = (_Float16)(f.y - (float)h.y);
    h.z = (_Float16)f.z; l.z = (_Float16)(f.z - (float)h.z);
    h.w = (_Float16)f.w; l.w = (_Float16)(f.w - (float)h.w);
    *(half4*)(dh + idx4 * 4) = h;
    *(half4*)(dl + idx4 * 4) = l;
}

// ---------------------------------------------------------------------------
// Top-2 state helpers: (d1, i1, d2).
// ---------------------------------------------------------------------------
__device__ __forceinline__ void t2_push(float& d1, int& i1, float& d2, float d, int v) {
    if (d < d1) { d2 = d1; d1 = d; i1 = v; }
    else if (d < d2) { d2 = d; }
}
__device__ __forceinline__ void t2_merge(float& d1, int& i1, float& d2,
                                         float od1, int oi1, float od2) {
    if (od1 < d1) { d2 = fminf(d1, od2); d1 = od1; i1 = oi1; }
    else          { d2 = fminf(d2, od1); }
}

// ---------------------------------------------------------------------------
// MFMA dist kernel: acc = Zh*Ch^T + Zl*Ch^T + Zh*Cl^T (fp32 acc);
// dist = esq[v] - 2*acc. Per-block 128x128 C-tile per vt; per-row top-2
// tracked across vt; partials (d1,i1,d2) written per (vs,row).
// Wave w: m-half (w>>1)*64, v-half (w&1)*64; 4x4 of 16x16x32 MFMAs.
// A/B frag (gemm_bt, guide-verified): row = lane&15, k = (lane>>4)*8 + j.
// C/D: col = lane&15, row = (lane>>4)*4 + reg.
// ---------------------------------------------------------------------------
__global__ __launch_bounds__(256)
void mfma_dist_kernel(const _Float16* __restrict__ zh, const _Float16* __restrict__ zl,
                      const _Float16* __restrict__ ch, const _Float16* __restrict__ cl,
                      const float* __restrict__ esq,
                      float* __restrict__ pd1, int* __restrict__ pi1,
                      float* __restrict__ pd2) {
    __shared__ _Float16 zsh[BM][LSH], zsl[BM][LSH];   // 10 KB each
    __shared__ _Float16 csh[BV][LSH], csl[BV][LSH];
    __shared__ float sc_d1[BM][2];
    __shared__ float sc_d2[BM][2];
    __shared__ int   sc_i1[BM][2];

    const int row0  = blockIdx.x * BM;
    const int vs    = blockIdx.y;
    const int vbase = vs * VRANGE;

    const int tid  = threadIdx.x;
    const int w    = tid >> 6;
    const int lane = tid & 63;
    const int lr   = lane & 15;          // frag row / C col
    const int quad = lane >> 4;          // 0..3
    const int kq   = quad * 8;           // frag k offset (halfs)
    const int mh   = (w >> 1) * 64;      // wave m-origin
    const int vh   = (w & 1) * 64;       // wave v-origin

    // staging: 512 16B-chunks per tile; thread covers q = tid, tid+256
    // chunk q -> row r = q>>2, 8-half group c = q&3
    const int sr0 = tid >> 2;            // rows: sr0, sr0+64
    const int sc  = tid & 3;

    // per-row global best (persistent in tid<128 threads)
    float gd1 = INFINITY, gd2 = INFINITY;
    int   gi1 = 0;

    for (int vt = 0; vt < NVT; ++vt) {
        const int v0 = vbase + vt * BV;

        // prefetch esq for this lane's 4 column groups
        float ev[4];
        #pragma unroll
        for (int j = 0; j < 4; ++j) ev[j] = esq[v0 + vh + j * 16 + lr];

        floatx4 acc[4][4];
        #pragma unroll
        for (int i = 0; i < 4; ++i)
            #pragma unroll
            for (int j = 0; j < 4; ++j) acc[i][j] = (floatx4)0.0f;

        #pragma unroll 1
        for (int kt = 0; kt < EMB / BK; ++kt) {
            // ---- stage 4 tiles (2 chunks per thread per tile) ----
            #pragma unroll
            for (int t = 0; t < 2; ++t) {
                const int r = sr0 + 64 * t;
                const size_t zoff = (size_t)(row0 + r) * EMB + kt * BK + sc * 8;
                const size_t coff = (size_t)(v0 + r) * EMB + kt * BK + sc * 8;
                *(float4*)&zsh[r][sc * 8] = *(const float4*)(zh + zoff);
                *(float4*)&zsl[r][sc * 8] = *(const float4*)(zl + zoff);
                *(float4*)&csh[r][sc * 8] = *(const float4*)(ch + coff);
                *(float4*)&csl[r][sc * 8] = *(const float4*)(cl + coff);
            }
            __syncthreads();

            // ---- 48 MFMAs: 4x4 tiles x 3 terms ----
            half8 ah[4], al[4];
            #pragma unroll
            for (int i = 0; i < 4; ++i) {
                ah[i] = *(const half8*)&zsh[mh + i * 16 + lr][kq];
                al[i] = *(const half8*)&zsl[mh + i * 16 + lr][kq];
            }
            #pragma unroll
            for (int j = 0; j < 4; ++j) {
                const half8 bh = *(const half8*)&csh[vh + j * 16 + lr][kq];
                const half8 bl = *(const half8*)&csl[vh + j * 16 + lr][kq];
                #pragma unroll
                for (int i = 0; i < 4; ++i) {
                    acc[i][j] = __builtin_amdgcn_mfma_f32_16x16x32_f16(ah[i], bh, acc[i][j], 0, 0, 0);
                    acc[i][j] = __builtin_amdgcn_mfma_f32_16x16x32_f16(al[i], bh, acc[i][j], 0, 0, 0);
                    acc[i][j] = __builtin_amdgcn_mfma_f32_16x16x32_f16(ah[i], bl, acc[i][j], 0, 0, 0);
                }
            }
            __syncthreads();
        }

        // ---- epilogue: per-row top-2 over this 128-col tile ----
        #pragma unroll
        for (int i = 0; i < 4; ++i) {
            #pragma unroll
            for (int reg = 0; reg < 4; ++reg) {
                // row m_local = mh + i*16 + quad*4 + reg; this lane holds 4 cols
                float d1 = INFINITY, d2 = INFINITY; int i1 = 0;
                #pragma unroll
                for (int j = 0; j < 4; ++j) {
                    const float d = ev[j] - 2.0f * acc[i][j][reg];
                    t2_push(d1, i1, d2, d, v0 + vh + j * 16 + lr);
                }
                // fold across the 16 lanes (lr) sharing this row
                #pragma unroll
                for (int off = 1; off < 16; off <<= 1) {
                    const float od1 = __shfl_xor(d1, off, 64);
                    const int   oi1 = __shfl_xor(i1, off, 64);
                    const float od2 = __shfl_xor(d2, off, 64);
                    t2_merge(d1, i1, d2, od1, oi1, od2);
                }
                if (lr == 0) {
                    const int r = mh + i * 16 + quad * 4 + reg;
                    sc_d1[r][w & 1] = d1;
                    sc_i1[r][w & 1] = i1;
                    sc_d2[r][w & 1] = d2;
                }
            }
        }
        __syncthreads();
        if (tid < BM) {
            float d1 = sc_d1[tid][0], d2 = sc_d2[tid][0]; int i1 = sc_i1[tid][0];
            t2_merge(d1, i1, d2, sc_d1[tid][1], sc_i1[tid][1], sc_d2[tid][1]);
            t2_merge(gd1, gi1, gd2, d1, i1, d2);
        }
        __syncthreads();
    }

    if (tid < BM) {
        const size_t o = (size_t)vs * N_ROWS + row0 + tid;
        pd1[o] = gd1; pi1[o] = gi1; pd2[o] = gd2;
    }
}

// ---------------------------------------------------------------------------
// Combine: merge VSPLIT top-2 partials per row. Wide margin -> commit
// token/zq/count; narrow margin -> flag row for exact rescue.
// ---------------------------------------------------------------------------
__global__ void combine_kernel(const float* __restrict__ pd1, const int* __restrict__ pi1,
                               const float* __restrict__ pd2,
                               const float* __restrict__ cb,
                               float* __restrict__ tokens, float* __restrict__ zq,
                               float* __restrict__ cnt,
                               int* __restrict__ flagcnt, int* __restrict__ flaglist) {
    const int wave = threadIdx.x >> 6;
    const int lane = threadIdx.x & 63;
    const int row  = blockIdx.x * 4 + wave;

    float d1 = INFINITY, d2 = INFINITY; int i1 = 0;
    #pragma unroll
    for (int s = 0; s < VSPLIT; ++s) {
        const size_t o = (size_t)s * N_ROWS + row;
        t2_merge(d1, i1, d2, pd1[o], pi1[o], pd2[o]);
    }
    const bool flagged = (d2 - d1) < TAU;
    if (flagged) {
        if (lane == 0) {
            const int pos = atomicAdd(flagcnt, 1);
            flaglist[pos] = row;
        }
        return;   // rescue kernel writes this row's outputs
    }
    if (lane == 0) {
        tokens[row] = (float)i1;
        atomicAdd(&cnt[i1], 1.0f);
    }
    const float4 v = *(const float4*)(cb + (size_t)i1 * EMB + lane * 4);
    *(float4*)(zq + (size_t)row * EMB + lane * 4) = v;
}

// ---------------------------------------------------------------------------
// Rescue: exact fp32 argmin over all 8192 codes for flagged rows.
// Fixed grid (graph-capture safe); ~0 rows expected, correct for any count.
// ---------------------------------------------------------------------------
__global__ void rescue_kernel(const int* __restrict__ flagcnt, const int* __restrict__ flaglist,
                              const float* __restrict__ z, const float* __restrict__ cb,
                              const float* __restrict__ esq,
                              float* __restrict__ tokens, float* __restrict__ zq,
                              float* __restrict__ cnt) {
    __shared__ float zrow[EMB];
    __shared__ float rd[256];
    __shared__ int   ri[256];
    const int tid = threadIdx.x;
    const int n = *flagcnt;
    for (int f = blockIdx.x; f < n; f += gridDim.x) {
        const int row = flaglist[f];
        zrow[tid] = z[(size_t)row * EMB + tid];
        __syncthreads();
        float best = INFINITY; int bi = VOCAB;
        for (int v = tid; v < VOCAB; v += 256) {
            float dot = 0.0f;
            #pragma unroll 8
            for (int k4 = 0; k4 < EMB / 4; ++k4) {
                const float4 c = *(const float4*)(cb + (size_t)v * EMB + k4 * 4);
                dot += zrow[k4 * 4 + 0] * c.x;
                dot += zrow[k4 * 4 + 1] * c.y;
                dot += zrow[k4 * 4 + 2] * c.z;
                dot += zrow[k4 * 4 + 3] * c.w;
            }
            const float d = esq[v] - 2.0f * dot;
            if (d < best) { best = d; bi = v; }   // v ascending per thread
        }
        rd[tid] = best; ri[tid] = bi;
        __syncthreads();
        for (int s = 128; s > 0; s >>= 1) {
            if (tid < s) {
                if (rd[tid + s] < rd[tid] ||
                    (rd[tid + s] == rd[tid] && ri[tid + s] < ri[tid])) {
                    rd[tid] = rd[tid + s]; ri[tid] = ri[tid + s];
                }
            }
            __syncthreads();
        }
        const int win = ri[0];
        if (tid == 0) {
            tokens[row] = (float)win;
            atomicAdd(&cnt[win], 1.0f);
        }
        if (tid < 64) {
            const float4 v4 = *(const float4*)(cb + (size_t)win * EMB + tid * 4);
            *(float4*)(zq + (size_t)row * EMB + tid * 4) = v4;
        }
        __syncthreads();
    }
}

// ===========================================================================
// Fallback (round-3 fp32 path) if ws is too small for the fp16 arrays.
// ===========================================================================
#define FLSTR 36
__global__ __launch_bounds__(256, 2)
void fb_dist_kernel(const float* __restrict__ z, const float* __restrict__ cb,
                    const float* __restrict__ esq,
                    float* __restrict__ pdist, int* __restrict__ pidx) {
    __shared__ float zs[BM][FLSTR];
    __shared__ float es[BV][FLSTR];
    __shared__ float rdist[16][16];
    __shared__ int   ridx [16][16];
    const int row0 = blockIdx.x * BM, vbase = blockIdx.y * VRANGE;
    const int tid = threadIdx.x, wave = tid >> 6, lane = tid & 63;
    const int wly = (lane >> 3) & 7, wlx = lane & 7;
    const int wbase = (wave >> 1) * 64, cbase = (wave & 1) * 64;
    const int arow = wbase + wly, bcol = cbase + wlx;
    const int rowSlot = (wave >> 1) * 8 + wly, colSlot = (wave & 1) * 8 + wlx;
    const int sc4 = tid & 7, sr0 = tid >> 3;
    float best[8]; int bidx[8];
    #pragma unroll
    for (int i = 0; i < 8; ++i) { best[i] = INFINITY; bidx[i] = 0; }
    for (int vt = 0; vt < NVT; ++vt) {
        const int v0 = vbase + vt * BV;
        float acc[8][8];
        #pragma unroll
        for (int i = 0; i < 8; ++i)
            #pragma unroll
            for (int j = 0; j < 8; ++j) acc[i][j] = 0.0f;
        #pragma unroll 1
        for (int kt = 0; kt < EMB / 32; ++kt) {
            #pragma unroll
            for (int t = 0; t < 4; ++t) {
                const int r = sr0 + 32 * t;
                *(float4*)&zs[r][sc4 * 4] = *(const float4*)(z  + (size_t)(row0 + r) * EMB + kt * 32 + sc4 * 4);
                *(float4*)&es[r][sc4 * 4] = *(const float4*)(cb + (size_t)(v0 + r) * EMB + kt * 32 + sc4 * 4);
            }
            __syncthreads();
            #pragma unroll 1
            for (int k0 = 0; k0 < 8; ++k0) {
                const int kk = k0 * 4;
                float a[8][4];
                #pragma unroll
                for (int i = 0; i < 8; ++i) {
                    const float4 a4 = *(const float4*)&zs[arow + 8 * i][kk];
                    a[i][0] = a4.x; a[i][1] = a4.y; a[i][2] = a4.z; a[i][3] = a4.w;
                }
                #pragma unroll
                for (int j = 0; j < 8; ++j) {
                    const float4 b4 = *(const float4*)&es[bcol + 8 * j][kk];
                    #pragma unroll
                    for (int i = 0; i < 8; ++i) {
                        acc[i][j] += a[i][0] * b4.x; acc[i][j] += a[i][1] * b4.y;
                        acc[i][j] += a[i][2] * b4.z; acc[i][j] += a[i][3] * b4.w;
                    }
                }
            }
            __syncthreads();
        }
        #pragma unroll
        for (int j = 0; j < 8; ++j) {
            const int v = v0 + bcol + 8 * j;
            const float evv = esq[v];
            #pragma unroll
            for (int i = 0; i < 8; ++i) {
                const float d = evv - 2.0f * acc[i][j];
                if (d < best[i]) { best[i] = d; bidx[i] = v; }
            }
        }
    }
    for (int i = 0; i < 8; ++i) {
        rdist[rowSlot][colSlot] = best[i];
        ridx [rowSlot][colSlot] = bidx[i];
        __syncthreads();
        if (colSlot == 0) {
            float bd = rdist[rowSlot][0]; int bi = ridx[rowSlot][0];
            #pragma unroll
            for (int t = 1; t < 16; ++t) {
                const float d = rdist[rowSlot][t]; const int ii = ridx[rowSlot][t];
                if (d < bd || (d == bd && ii < bi)) { bd = d; bi = ii; }
            }
            const int row = row0 + wbase + 8 * i + wly;
            pdist[(size_t)blockIdx.y * N_ROWS + row] = bd;
            pidx [(size_t)blockIdx.y * N_ROWS + row] = bi;
        }
        __syncthreads();
    }
}

__global__ void fb_combine_kernel(const float* __restrict__ pdist, const int* __restrict__ pidx,
                                  const float* __restrict__ cb,
                                  float* __restrict__ tokens, float* __restrict__ zq,
                                  float* __restrict__ cnt) {
    const int wave = threadIdx.x >> 6, lane = threadIdx.x & 63;
    const int row = blockIdx.x * 4 + wave;
    float bd = INFINITY; int bi = 0;
    #pragma unroll
    for (int s = 0; s < VSPLIT; ++s) {
        const float d = pdist[(size_t)s * N_ROWS + row];
        const int ii  = pidx [(size_t)s * N_ROWS + row];
        if (d < bd || (d == bd && ii < bi)) { bd = d; bi = ii; }
    }
    if (lane == 0) { tokens[row] = (float)bi; atomicAdd(&cnt[bi], 1.0f); }
    const float4 v = *(const float4*)(cb + (size_t)bi * EMB + lane * 4);
    *(float4*)(zq + (size_t)row * EMB + lane * 4) = v;
}

// ---------------------------------------------------------------------------
// d_out: [0,N) tokens | [N, N+N*EMB) zq | +VOCAB ref_count
// ws (fp16 path): zh|zl (8.39 MB ea) | ch|cl (4.19 MB ea) | esq | pd1|pd2 (f32)
//                 | pi1 | flagcnt(16) | flaglist  ~= 26.7 MB
// ---------------------------------------------------------------------------
extern "C" void kernel_launch(void* const* d_in, const int* in_sizes, int n_in,
                              void* d_out, int out_size, void* d_ws, size_t ws_size,
                              hipStream_t stream) {
    const float* z  = (const float*)d_in[0];
    const float* cb = (const float*)d_in[1];

    float* out    = (float*)d_out;
    float* tokens = out;
    float* zq     = out + N_ROWS;
    float* cnt    = out + N_ROWS + (size_t)N_ROWS * EMB;

    hipMemsetAsync(cnt, 0, VOCAB * sizeof(float), stream);

    const size_t ZE = (size_t)N_ROWS * EMB, CE = (size_t)VOCAB * EMB, P = (size_t)VSPLIT * N_ROWS;
    const size_t NEED = (2 * ZE + 2 * CE) * sizeof(_Float16) + VOCAB * 4
                      + 3 * P * 4 + 16 + N_ROWS * 4 + 256;

    if (ws_size >= NEED) {
        char* p = (char*)d_ws;
        _Float16* zh = (_Float16*)p;            p += ZE * 2;
        _Float16* zl = (_Float16*)p;            p += ZE * 2;
        _Float16* ch = (_Float16*)p;            p += CE * 2;
        _Float16* cl = (_Float16*)p;            p += CE * 2;
        float* esq   = (float*)p;               p += VOCAB * 4;
        float* pd1   = (float*)p;               p += P * 4;
        float* pd2   = (float*)p;               p += P * 4;
        int*   pi1   = (int*)p;                 p += P * 4;
        int*   flagcnt = (int*)p;               p += 16;
        int*   flaglist = (int*)p;

        hipMemsetAsync(flagcnt, 0, sizeof(int), stream);
        esq_kernel<<<VOCAB / 4, 256, 0, stream>>>(cb, esq);
        split_kernel<<<(int)((ZE + CE) / 4 / 256), 256, 0, stream>>>(z, cb, zh, zl, ch, cl);
        mfma_dist_kernel<<<dim3(N_ROWS / BM, VSPLIT), 256, 0, stream>>>(
            zh, zl, ch, cl, esq, pd1, pi1, pd2);
        combine_kernel<<<N_ROWS / 4, 256, 0, stream>>>(
            pd1, pi1, pd2, cb, tokens, zq, cnt, flagcnt, flaglist);
        rescue_kernel<<<128, 256, 0, stream>>>(
            flagcnt, flaglist, z, cb, esq, tokens, zq, cnt);
    } else {
        float* esq   = (float*)d_ws;
        float* pdist = esq + VOCAB;
        int*   pidx  = (int*)(pdist + P);
        esq_kernel<<<VOCAB / 4, 256, 0, stream>>>(cb, esq);
        fb_dist_kernel<<<dim3(N_ROWS / BM, VSPLIT), 256, 0, stream>>>(z, cb, esq, pdist, pidx);
        fb_combine_kernel<<<N_ROWS / 4, 256, 0, stream>>>(pdist, pidx, cb, tokens, zq, cnt);
    }
}

// Round 5
// 441.230 us; speedup vs baseline: 55.8530x; 1.3944x over previous
//
#include <hip/hip_runtime.h>
#include <math.h>

#define N_ROWS 16384
#define VOCAB  8192
#define EMB    256

// ---- MFMA path tiling ----
#define BM 128
#define BV 128
#define BK 32                      // halfs per K-step
#define VSPLIT 8                   // grid (128, 8)
#define VRANGE (VOCAB / VSPLIT)    // 1024
#define NVT    (VRANGE / BV)       // 8
#define LSH    40                  // LDS row stride in halfs (80 B, 16B-aligned, period-8 banks)
#define TAU    0.01f               // rescue margin (approx dist error <= ~1e-3)

typedef _Float16 half8 __attribute__((ext_vector_type(8)));
typedef _Float16 half4 __attribute__((ext_vector_type(4)));
typedef float floatx4 __attribute__((ext_vector_type(4)));

// ---------------------------------------------------------------------------
// esq[v] = ||cb[v]||^2 (fp32, exact). One wave per row.
// ---------------------------------------------------------------------------
__global__ void esq_kernel(const float* __restrict__ cb, float* __restrict__ esq) {
    const int wave = threadIdx.x >> 6;
    const int lane = threadIdx.x & 63;
    const int row  = blockIdx.x * 4 + wave;
    const float4 v = *(const float4*)(cb + (size_t)row * EMB + lane * 4);
    float s = v.x * v.x + v.y * v.y + v.z * v.z + v.w * v.w;
    #pragma unroll
    for (int off = 32; off > 0; off >>= 1) s += __shfl_down(s, off, 64);
    if (lane == 0) esq[row] = s;
}

// ---------------------------------------------------------------------------
// Split fp32 -> fp16 hi + fp16 lo for z and cb.
// ---------------------------------------------------------------------------
__global__ void split_kernel(const float* __restrict__ z, const float* __restrict__ cb,
                             _Float16* __restrict__ zh, _Float16* __restrict__ zl,
                             _Float16* __restrict__ ch, _Float16* __restrict__ cl) {
    const size_t gid = (size_t)blockIdx.x * blockDim.x + threadIdx.x;
    const size_t ZQ4 = (size_t)N_ROWS * EMB / 4;
    const float* src; _Float16 *dh, *dl; size_t idx4;
    if (gid < ZQ4) { src = z;  dh = zh; dl = zl; idx4 = gid; }
    else           { src = cb; dh = ch; dl = cl; idx4 = gid - ZQ4; }
    const float4 f = *(const float4*)(src + idx4 * 4);
    half4 h, l;
    h.x = (_Float16)f.x; l.x = (_Float16)(f.x - (float)h.x);
    h.y = (_Float16)f.y; l.y = (_Float16)(f.y - (float)h.y);
    h.z = (_Float16)f.z; l.z = (_Float16)(f.z - (float)h.z);
    h.w = (_Float16)f.w; l.w = (_Float16)(f.w - (float)h.w);
    *(half4*)(dh + idx4 * 4) = h;
    *(half4*)(dl + idx4 * 4) = l;
}

// ---------------------------------------------------------------------------
// Top-2 helpers.
// ---------------------------------------------------------------------------
__device__ __forceinline__ void t2_push(float& d1, int& i1, float& d2, float d, int v) {
    if (d < d1) { d2 = d1; d1 = d; i1 = v; }
    else if (d < d2) { d2 = d; }
}
__device__ __forceinline__ void t2_merge(float& d1, int& i1, float& d2,
                                         float od1, int oi1, float od2) {
    if (od1 < d1) { d2 = fminf(d1, od2); d1 = od1; i1 = oi1; }
    else          { d2 = fminf(d2, od1); }
}

// ---------------------------------------------------------------------------
// MFMA dist kernel: acc = Zh*Ch^T + Zl*Ch^T + Zh*Cl^T; dist = esq - 2*acc.
// LDS: 4 tiles x 128 x 40 halfs = 40960 B exactly; epilogue scratch ALIASES
// tile 0 (dead between the kt-loop's last barrier and the next vt staging).
// launch_bounds(256,3): budget 168 regs = 64 AGPR acc + ~104 VGPR (inventory:
// ah/al 32 + bh/bl 8 + addressing ~30 + top2 ~10). Round 2's spill disaster
// was bound=4 (128 budget, infeasible); 168 should fit. Tripwire: WRITE_SIZE.
// ---------------------------------------------------------------------------
__global__ __launch_bounds__(256, 3)
void mfma_dist_kernel(const _Float16* __restrict__ zh, const _Float16* __restrict__ zl,
                      const _Float16* __restrict__ ch, const _Float16* __restrict__ cl,
                      const float* __restrict__ esq,
                      float* __restrict__ pd1, int* __restrict__ pi1,
                      float* __restrict__ pd2) {
    __shared__ _Float16 smem[4 * BM * LSH];          // 40960 B
    _Float16 (*zsh)[LSH] = (_Float16(*)[LSH])(smem + 0 * BM * LSH);
    _Float16 (*zsl)[LSH] = (_Float16(*)[LSH])(smem + 1 * BM * LSH);
    _Float16 (*csh)[LSH] = (_Float16(*)[LSH])(smem + 2 * BM * LSH);
    _Float16 (*csl)[LSH] = (_Float16(*)[LSH])(smem + 3 * BM * LSH);
    // epilogue scratch aliases tile 0 (3 KB < 10 KB)
    float* sc_d1 = (float*)smem;                      // [BM][2]
    float* sc_d2 = sc_d1 + BM * 2;
    int*   sc_i1 = (int*)(sc_d2 + BM * 2);

    const int row0  = blockIdx.x * BM;
    const int vs    = blockIdx.y;
    const int vbase = vs * VRANGE;

    const int tid  = threadIdx.x;
    const int w    = tid >> 6;
    const int lane = tid & 63;
    const int lr   = lane & 15;
    const int quad = lane >> 4;
    const int kq   = quad * 8;
    const int mh   = (w >> 1) * 64;
    const int vh   = (w & 1) * 64;

    const int sr0 = tid >> 2;
    const int sc  = tid & 3;

    float gd1 = INFINITY, gd2 = INFINITY;
    int   gi1 = 0;

    for (int vt = 0; vt < NVT; ++vt) {
        const int v0 = vbase + vt * BV;

        floatx4 acc[4][4];
        #pragma unroll
        for (int i = 0; i < 4; ++i)
            #pragma unroll
            for (int j = 0; j < 4; ++j) acc[i][j] = (floatx4)0.0f;

        #pragma unroll 1
        for (int kt = 0; kt < EMB / BK; ++kt) {
            #pragma unroll
            for (int t = 0; t < 2; ++t) {
                const int r = sr0 + 64 * t;
                const size_t zoff = (size_t)(row0 + r) * EMB + kt * BK + sc * 8;
                const size_t coff = (size_t)(v0 + r) * EMB + kt * BK + sc * 8;
                *(float4*)&zsh[r][sc * 8] = *(const float4*)(zh + zoff);
                *(float4*)&zsl[r][sc * 8] = *(const float4*)(zl + zoff);
                *(float4*)&csh[r][sc * 8] = *(const float4*)(ch + coff);
                *(float4*)&csl[r][sc * 8] = *(const float4*)(cl + coff);
            }
            __syncthreads();

            half8 ah[4], al[4];
            #pragma unroll
            for (int i = 0; i < 4; ++i) {
                ah[i] = *(const half8*)&zsh[mh + i * 16 + lr][kq];
                al[i] = *(const half8*)&zsl[mh + i * 16 + lr][kq];
            }
            #pragma unroll
            for (int j = 0; j < 4; ++j) {
                const half8 bh = *(const half8*)&csh[vh + j * 16 + lr][kq];
                const half8 bl = *(const half8*)&csl[vh + j * 16 + lr][kq];
                #pragma unroll
                for (int i = 0; i < 4; ++i) {
                    acc[i][j] = __builtin_amdgcn_mfma_f32_16x16x32_f16(ah[i], bh, acc[i][j], 0, 0, 0);
                    acc[i][j] = __builtin_amdgcn_mfma_f32_16x16x32_f16(al[i], bh, acc[i][j], 0, 0, 0);
                    acc[i][j] = __builtin_amdgcn_mfma_f32_16x16x32_f16(ah[i], bl, acc[i][j], 0, 0, 0);
                }
            }
            __syncthreads();
        }

        // ---- epilogue (tiles dead; scratch aliasing safe after barrier) ----
        float ev[4];
        #pragma unroll
        for (int j = 0; j < 4; ++j) ev[j] = esq[v0 + vh + j * 16 + lr];

        #pragma unroll
        for (int i = 0; i < 4; ++i) {
            #pragma unroll
            for (int reg = 0; reg < 4; ++reg) {
                float d1 = INFINITY, d2 = INFINITY; int i1 = 0;
                #pragma unroll
                for (int j = 0; j < 4; ++j) {
                    const float d = ev[j] - 2.0f * acc[i][j][reg];
                    t2_push(d1, i1, d2, d, v0 + vh + j * 16 + lr);
                }
                #pragma unroll
                for (int off = 1; off < 16; off <<= 1) {
                    const float od1 = __shfl_xor(d1, off, 64);
                    const int   oi1 = __shfl_xor(i1, off, 64);
                    const float od2 = __shfl_xor(d2, off, 64);
                    t2_merge(d1, i1, d2, od1, oi1, od2);
                }
                if (lr == 0) {
                    const int r = mh + i * 16 + quad * 4 + reg;
                    sc_d1[r * 2 + (w & 1)] = d1;
                    sc_i1[r * 2 + (w & 1)] = i1;
                    sc_d2[r * 2 + (w & 1)] = d2;
                }
            }
        }
        __syncthreads();
        if (tid < BM) {
            float d1 = sc_d1[tid * 2], d2 = sc_d2[tid * 2]; int i1 = sc_i1[tid * 2];
            t2_merge(d1, i1, d2, sc_d1[tid * 2 + 1], sc_i1[tid * 2 + 1], sc_d2[tid * 2 + 1]);
            t2_merge(gd1, gi1, gd2, d1, i1, d2);
        }
        __syncthreads();
    }

    if (tid < BM) {
        const size_t o = (size_t)vs * N_ROWS + row0 + tid;
        pd1[o] = gd1; pi1[o] = gi1; pd2[o] = gd2;
    }
}

// ---------------------------------------------------------------------------
// Combine: merge VSPLIT top-2 partials; wide margin -> commit, narrow -> flag.
// ---------------------------------------------------------------------------
__global__ void combine_kernel(const float* __restrict__ pd1, const int* __restrict__ pi1,
                               const float* __restrict__ pd2,
                               const float* __restrict__ cb,
                               float* __restrict__ tokens, float* __restrict__ zq,
                               float* __restrict__ cnt,
                               int* __restrict__ flagcnt, int* __restrict__ flaglist) {
    const int wave = threadIdx.x >> 6;
    const int lane = threadIdx.x & 63;
    const int row  = blockIdx.x * 4 + wave;

    float d1 = INFINITY, d2 = INFINITY; int i1 = 0;
    #pragma unroll
    for (int s = 0; s < VSPLIT; ++s) {
        const size_t o = (size_t)s * N_ROWS + row;
        t2_merge(d1, i1, d2, pd1[o], pi1[o], pd2[o]);
    }
    if ((d2 - d1) < TAU) {
        if (lane == 0) {
            const int pos = atomicAdd(flagcnt, 1);
            flaglist[pos] = row;
        }
        return;   // rescue path writes this row
    }
    if (lane == 0) {
        tokens[row] = (float)i1;
        atomicAdd(&cnt[i1], 1.0f);
    }
    const float4 v = *(const float4*)(cb + (size_t)i1 * EMB + lane * 4);
    *(float4*)(zq + (size_t)row * EMB + lane * 4) = v;
}

// ---------------------------------------------------------------------------
// Rescue v2: exact fp32 argmin for flagged rows, parallel + coalesced.
// Job = (flagged row, 512-code chunk); grid-stride over n*16 jobs.
// Wave-per-code: lanes cover the 256 dims (coalesced 1 KB reads), shuffle
// reduce; cross-block merge via 64-bit atomicMin of packed (dist, idx).
// ---------------------------------------------------------------------------
__global__ void rescue2_kernel(const int* __restrict__ flagcnt, const int* __restrict__ flaglist,
                               const float* __restrict__ z, const float* __restrict__ cb,
                               const float* __restrict__ esq,
                               unsigned long long* __restrict__ rkey) {
    const int tid  = threadIdx.x;
    const int w    = tid >> 6;
    const int lane = tid & 63;
    const int n = *flagcnt;
    const int njobs = n * 16;
    for (int j = blockIdx.x; j < njobs; j += gridDim.x) {
        const int row = flaglist[j >> 4];
        const int v0  = (j & 15) * 512 + w * 128;
        const float4 zl4 = *(const float4*)(z + (size_t)row * EMB + lane * 4);
        float bd = INFINITY; int bv = 0;
        for (int c = 0; c < 128; ++c) {
            const int v = v0 + c;
            const float4 cv = *(const float4*)(cb + (size_t)v * EMB + lane * 4);
            float p = zl4.x * cv.x + zl4.y * cv.y + zl4.z * cv.z + zl4.w * cv.w;
            #pragma unroll
            for (int off = 32; off > 0; off >>= 1) p += __shfl_down(p, off, 64);
            if (lane == 0) {
                const float d = esq[v] - 2.0f * p;
                if (d < bd) { bd = d; bv = v; }   // v ascending: lowest tie index
            }
        }
        if (lane == 0) {
            unsigned int u = __float_as_uint(bd);
            u = (u & 0x80000000u) ? ~u : (u | 0x80000000u);   // order-preserving
            const unsigned long long key =
                ((unsigned long long)u << 32) | (unsigned int)bv;
            atomicMin(rkey + row, key);
        }
    }
}

// ---------------------------------------------------------------------------
// Rescue writer: one wave per flagged row.
// ---------------------------------------------------------------------------
__global__ void rescue_write_kernel(const int* __restrict__ flagcnt,
                                    const int* __restrict__ flaglist,
                                    const unsigned long long* __restrict__ rkey,
                                    const float* __restrict__ cb,
                                    float* __restrict__ tokens, float* __restrict__ zq,
                                    float* __restrict__ cnt) {
    const int w    = threadIdx.x >> 6;
    const int lane = threadIdx.x & 63;
    const int n = *flagcnt;
    for (int f = blockIdx.x * 4 + w; f < n; f += gridDim.x * 4) {
        const int row = flaglist[f];
        const int v = (int)(unsigned int)(rkey[row] & 0xFFFFFFFFull);
        if (lane == 0) {
            tokens[row] = (float)v;
            atomicAdd(&cnt[v], 1.0f);
        }
        const float4 c4 = *(const float4*)(cb + (size_t)v * EMB + lane * 4);
        *(float4*)(zq + (size_t)row * EMB + lane * 4) = c4;
    }
}

// ===========================================================================
// Fallback (round-3 fp32 path) if ws is too small.
// ===========================================================================
#define FLSTR 36
__global__ __launch_bounds__(256, 2)
void fb_dist_kernel(const float* __restrict__ z, const float* __restrict__ cb,
                    const float* __restrict__ esq,
                    float* __restrict__ pdist, int* __restrict__ pidx) {
    __shared__ float zs[BM][FLSTR];
    __shared__ float es[BV][FLSTR];
    __shared__ float rdist[16][16];
    __shared__ int   ridx [16][16];
    const int row0 = blockIdx.x * BM, vbase = blockIdx.y * VRANGE;
    const int tid = threadIdx.x, wave = tid >> 6, lane = tid & 63;
    const int wly = (lane >> 3) & 7, wlx = lane & 7;
    const int wbase = (wave >> 1) * 64, cbase = (wave & 1) * 64;
    const int arow = wbase + wly, bcol = cbase + wlx;
    const int rowSlot = (wave >> 1) * 8 + wly, colSlot = (wave & 1) * 8 + wlx;
    const int sc4 = tid & 7, sr0 = tid >> 3;
    float best[8]; int bidx[8];
    #pragma unroll
    for (int i = 0; i < 8; ++i) { best[i] = INFINITY; bidx[i] = 0; }
    for (int vt = 0; vt < NVT; ++vt) {
        const int v0 = vbase + vt * BV;
        float acc[8][8];
        #pragma unroll
        for (int i = 0; i < 8; ++i)
            #pragma unroll
            for (int j = 0; j < 8; ++j) acc[i][j] = 0.0f;
        #pragma unroll 1
        for (int kt = 0; kt < EMB / 32; ++kt) {
            #pragma unroll
            for (int t = 0; t < 4; ++t) {
                const int r = sr0 + 32 * t;
                *(float4*)&zs[r][sc4 * 4] = *(const float4*)(z  + (size_t)(row0 + r) * EMB + kt * 32 + sc4 * 4);
                *(float4*)&es[r][sc4 * 4] = *(const float4*)(cb + (size_t)(v0 + r) * EMB + kt * 32 + sc4 * 4);
            }
            __syncthreads();
            #pragma unroll 1
            for (int k0 = 0; k0 < 8; ++k0) {
                const int kk = k0 * 4;
                float a[8][4];
                #pragma unroll
                for (int i = 0; i < 8; ++i) {
                    const float4 a4 = *(const float4*)&zs[arow + 8 * i][kk];
                    a[i][0] = a4.x; a[i][1] = a4.y; a[i][2] = a4.z; a[i][3] = a4.w;
                }
                #pragma unroll
                for (int j = 0; j < 8; ++j) {
                    const float4 b4 = *(const float4*)&es[bcol + 8 * j][kk];
                    #pragma unroll
                    for (int i = 0; i < 8; ++i) {
                        acc[i][j] += a[i][0] * b4.x; acc[i][j] += a[i][1] * b4.y;
                        acc[i][j] += a[i][2] * b4.z; acc[i][j] += a[i][3] * b4.w;
                    }
                }
            }
            __syncthreads();
        }
        #pragma unroll
        for (int j = 0; j < 8; ++j) {
            const int v = v0 + bcol + 8 * j;
            const float evv = esq[v];
            #pragma unroll
            for (int i = 0; i < 8; ++i) {
                const float d = evv - 2.0f * acc[i][j];
                if (d < best[i]) { best[i] = d; bidx[i] = v; }
            }
        }
    }
    for (int i = 0; i < 8; ++i) {
        rdist[rowSlot][colSlot] = best[i];
        ridx [rowSlot][colSlot] = bidx[i];
        __syncthreads();
        if (colSlot == 0) {
            float bd = rdist[rowSlot][0]; int bi = ridx[rowSlot][0];
            #pragma unroll
            for (int t = 1; t < 16; ++t) {
                const float d = rdist[rowSlot][t]; const int ii = ridx[rowSlot][t];
                if (d < bd || (d == bd && ii < bi)) { bd = d; bi = ii; }
            }
            const int row = row0 + wbase + 8 * i + wly;
            pdist[(size_t)blockIdx.y * N_ROWS + row] = bd;
            pidx [(size_t)blockIdx.y * N_ROWS + row] = bi;
        }
        __syncthreads();
    }
}

__global__ void fb_combine_kernel(const float* __restrict__ pdist, const int* __restrict__ pidx,
                                  const float* __restrict__ cb,
                                  float* __restrict__ tokens, float* __restrict__ zq,
                                  float* __restrict__ cnt) {
    const int wave = threadIdx.x >> 6, lane = threadIdx.x & 63;
    const int row = blockIdx.x * 4 + wave;
    float bd = INFINITY; int bi = 0;
    #pragma unroll
    for (int s = 0; s < VSPLIT; ++s) {
        const float d = pdist[(size_t)s * N_ROWS + row];
        const int ii  = pidx [(size_t)s * N_ROWS + row];
        if (d < bd || (d == bd && ii < bi)) { bd = d; bi = ii; }
    }
    if (lane == 0) { tokens[row] = (float)bi; atomicAdd(&cnt[bi], 1.0f); }
    const float4 v = *(const float4*)(cb + (size_t)bi * EMB + lane * 4);
    *(float4*)(zq + (size_t)row * EMB + lane * 4) = v;
}

// ---------------------------------------------------------------------------
// d_out: [0,N) tokens | [N, N+N*EMB) zq | +VOCAB ref_count
// ws: zh|zl|ch|cl (fp16) | esq | pd1|pd2 | pi1 | rkey(u64) | flagcnt | flaglist
// ---------------------------------------------------------------------------
extern "C" void kernel_launch(void* const* d_in, const int* in_sizes, int n_in,
                              void* d_out, int out_size, void* d_ws, size_t ws_size,
                              hipStream_t stream) {
    const float* z  = (const float*)d_in[0];
    const float* cb = (const float*)d_in[1];

    float* out    = (float*)d_out;
    float* tokens = out;
    float* zq     = out + N_ROWS;
    float* cnt    = out + N_ROWS + (size_t)N_ROWS * EMB;

    hipMemsetAsync(cnt, 0, VOCAB * sizeof(float), stream);

    const size_t ZE = (size_t)N_ROWS * EMB, CE = (size_t)VOCAB * EMB, P = (size_t)VSPLIT * N_ROWS;
    const size_t NEED = (2 * ZE + 2 * CE) * sizeof(_Float16) + VOCAB * 4
                      + 3 * P * 4 + (size_t)N_ROWS * 8 + 16 + N_ROWS * 4 + 256;

    if (ws_size >= NEED) {
        char* p = (char*)d_ws;
        _Float16* zh = (_Float16*)p;            p += ZE * 2;
        _Float16* zl = (_Float16*)p;            p += ZE * 2;
        _Float16* ch = (_Float16*)p;            p += CE * 2;
        _Float16* cl = (_Float16*)p;            p += CE * 2;
        float* esq   = (float*)p;               p += VOCAB * 4;
        float* pd1   = (float*)p;               p += P * 4;
        float* pd2   = (float*)p;               p += P * 4;
        int*   pi1   = (int*)p;                 p += P * 4;
        unsigned long long* rkey = (unsigned long long*)p;  p += (size_t)N_ROWS * 8;
        int*   flagcnt = (int*)p;               p += 16;
        int*   flaglist = (int*)p;

        hipMemsetAsync(flagcnt, 0, sizeof(int), stream);
        hipMemsetAsync(rkey, 0xFF, (size_t)N_ROWS * 8, stream);   // +inf keys for atomicMin

        esq_kernel<<<VOCAB / 4, 256, 0, stream>>>(cb, esq);
        split_kernel<<<(int)((ZE + CE) / 4 / 256), 256, 0, stream>>>(z, cb, zh, zl, ch, cl);
        mfma_dist_kernel<<<dim3(N_ROWS / BM, VSPLIT), 256, 0, stream>>>(
            zh, zl, ch, cl, esq, pd1, pi1, pd2);
        combine_kernel<<<N_ROWS / 4, 256, 0, stream>>>(
            pd1, pi1, pd2, cb, tokens, zq, cnt, flagcnt, flaglist);
        rescue2_kernel<<<256, 256, 0, stream>>>(flagcnt, flaglist, z, cb, esq, rkey);
        rescue_write_kernel<<<32, 256, 0, stream>>>(flagcnt, flaglist, rkey, cb, tokens, zq, cnt);
    } else {
        float* esq   = (float*)d_ws;
        float* pdist = esq + VOCAB;
        int*   pidx  = (int*)(pdist + P);
        esq_kernel<<<VOCAB / 4, 256, 0, stream>>>(cb, esq);
        fb_dist_kernel<<<dim3(N_ROWS / BM, VSPLIT), 256, 0, stream>>>(z, cb, esq, pdist, pidx);
        fb_combine_kernel<<<N_ROWS / 4, 256, 0, stream>>>(pdist, pidx, cb, tokens, zq, cnt);
    }
}